// Round 3
// baseline (955.318 us; speedup 1.0000x reference)
//
#include <hip/hip_runtime.h>
#include <math.h>

// NCE loss: N=16384 rows x D=4096, fp32.
// loss_row = logsumexp(logits/alpha) - logits[argmax(labels)]/alpha ; out = mean.
// Pure streaming: labels+logits = 512 MB read, mask untouched. HBM floor ~81 us.
//
// R3 change (single variable vs R2): FUSED finalize. The separate 1-block
// nce_finalize kernel serialized behind the main grid (launch latency + a
// latency-bound 64 KB read ~ 10-20 us per invocation). Now each block writes
// one partial (fixed-order sum of its 4 row losses) and the LAST block to
// finish (device-scope counter) reduces all 4096 partials in a fixed
// strided+butterfly order -> bitwise-deterministic result independent of
// which block runs last. Counter self-resets for graph replay.
// Main loop unchanged from R2: wave-per-row, nontemporal loads, 2-chunk
// software pipeline, zero LDS in the streaming phase.

typedef float vf4 __attribute__((ext_vector_type(4)));

constexpr int   Dk    = 4096;
constexpr int   Nk    = 16384;
constexpr int   BLOCK = 256;        // 4 waves -> 4 rows per block
constexpr int   NBmax = Nk / 4;     // 4096 blocks
constexpr float LOG2E = 1.44269504088896340736f;

__device__ float g_part[NBmax];     // per-block partial sums (module global)
__device__ int   g_cnt = 0;         // arrival counter, self-resetting

__global__ __launch_bounds__(BLOCK, 4) void nce_fused(
    const float* __restrict__ labels, const float* __restrict__ logits,
    const float* __restrict__ alpha, float* __restrict__ out,
    int nb, float inv_n)
{
    const int t   = threadIdx.x;
    const int ln  = t & 63;
    const int row = blockIdx.x * 4 + (t >> 6);
    const size_t base = (size_t)row * (Dk / 4) + ln;
    const vf4* lg4  = reinterpret_cast<const vf4*>(logits) + base;
    const vf4* lab4 = reinterpret_cast<const vf4*>(labels) + base;

    const float inv_a = 1.0f / alpha[0];
    const float ia2   = inv_a * LOG2E;   // exp(x/a) == exp2(x * ia2)

    float m = -INFINITY, s = 0.0f;       // online logsumexp state
    float lmax = -INFINITY, lval = 0.0f; // label argmax triple
    int   lidx = 0;

    vf4 ga[4], la[4], gb[4], lb[4];

#define LOADC(G, L, c)                                                   \
    _Pragma("unroll")                                                    \
    for (int k = 0; k < 4; ++k) {                                        \
        G[k] = __builtin_nontemporal_load(lg4 + (c) * 256 + k * 64);     \
        L[k] = __builtin_nontemporal_load(lab4 + (c) * 256 + k * 64);    \
    }

    // Online-softmax update over one 16-elem register chunk.
    auto process = [&](const vf4 (&g)[4], const vf4 (&l)[4], int c) {
        float cm = -INFINITY;
#pragma unroll
        for (int k = 0; k < 4; ++k)
#pragma unroll
            for (int e = 0; e < 4; ++e) cm = fmaxf(cm, g[k][e]);
        const float nm = fmaxf(m, cm);
        s *= exp2f((m - nm) * ia2);          // chunk 0: 0 * 0 == 0
        const float c2 = -nm * ia2;
#pragma unroll
        for (int k = 0; k < 4; ++k) {
#pragma unroll
            for (int e = 0; e < 4; ++e) {
                const float ge = g[k][e];
                const float le = l[k][e];
                s += exp2f(fmaf(ge, ia2, c2));
                // per-lane idx strictly increases -> '>' keeps first
                // occurrence (matches jnp.argmax tie rule).
                if (le > lmax) {
                    lmax = le; lval = ge;
                    lidx = 4 * ((c) * 256 + k * 64 + ln) + e;
                }
            }
        }
        m = nm;
    };

    LOADC(ga, la, 0)                 // prologue
    LOADC(gb, lb, 1)                 // chunk 1 in flight...
    process(ga, la, 0);              // ...while chunk 0 is consumed
    LOADC(ga, la, 2)
    process(gb, lb, 1);
    LOADC(gb, lb, 3)
    process(ga, la, 2);
    process(gb, lb, 3);
#undef LOADC

    // Wave butterfly reduce: row max + argmax triple (all lanes converge).
    const float ml = m;
#pragma unroll
    for (int off = 1; off < 64; off <<= 1) {
        m = fmaxf(m, __shfl_xor(m, off));
        const float om = __shfl_xor(lmax, off);
        const int   oi = __shfl_xor(lidx, off);
        const float ov = __shfl_xor(lval, off);
        if (om > lmax || (om == lmax && oi < lidx)) { lmax = om; lidx = oi; lval = ov; }
    }
    s *= exp2f((ml - m) * ia2);      // rescale lane sum to row max
#pragma unroll
    for (int off = 1; off < 64; off <<= 1) s += __shfl_xor(s, off);

    const float rowloss = (m - lval) * inv_a + logf(s);

    // ---- block partial (fixed order) + last-block arrival ----
    __shared__ float s_v[BLOCK / 64];
    __shared__ int   s_last;
    if (ln == 0) s_v[t >> 6] = rowloss;
    __syncthreads();
    if (t == 0) {
        const float part = (s_v[0] + s_v[1]) + (s_v[2] + s_v[3]);
        __hip_atomic_store(&g_part[blockIdx.x], part,
                           __ATOMIC_RELEASE, __HIP_MEMORY_SCOPE_AGENT);
        const int old = __hip_atomic_fetch_add(&g_cnt, 1,
                           __ATOMIC_ACQ_REL, __HIP_MEMORY_SCOPE_AGENT);
        s_last = (old == nb - 1);
    }
    __syncthreads();

    // ---- last block: deterministic final reduction over 4096 partials ----
    if (s_last) {
        float v = 0.0f;
        for (int i = t; i < nb; i += BLOCK)       // fixed strided order
            v += __hip_atomic_load(&g_part[i],
                     __ATOMIC_RELAXED, __HIP_MEMORY_SCOPE_AGENT);
#pragma unroll
        for (int off = 1; off < 64; off <<= 1) v += __shfl_xor(v, off);
        if (ln == 0) s_v[t >> 6] = v;
        __syncthreads();
        if (t == 0) {
            out[0] = ((s_v[0] + s_v[1]) + (s_v[2] + s_v[3])) * inv_n;
            __hip_atomic_store(&g_cnt, 0,            // reset for next replay
                               __ATOMIC_RELAXED, __HIP_MEMORY_SCOPE_AGENT);
        }
    }
}

extern "C" void kernel_launch(void* const* d_in, const int* in_sizes, int n_in,
                              void* d_out, int out_size, void* d_ws, size_t ws_size,
                              hipStream_t stream) {
    const float* labels = (const float*)d_in[0];
    const float* logits = (const float*)d_in[1];
    // d_in[2] = mask (unused by the reference math)
    const float* alpha  = (const float*)d_in[3];
    float* out  = (float*)d_out;
    (void)d_ws; (void)ws_size;       // workspace deliberately untouched

    int N = in_sizes[0] / Dk;        // 16384
    if (N > Nk) N = Nk;              // module-array capacity guard
    const int nb = N / 4;

    nce_fused<<<nb, BLOCK, 0, stream>>>(labels, logits, alpha, out,
                                        nb, 1.0f / (float)N);
}